// Round 15
// baseline (4487.279 us; speedup 1.0000x reference)
//
#include <hip/hip_runtime.h>

#define BB 256
#define TT 2048
#define HD 100

typedef _Float16 f16x8 __attribute__((ext_vector_type(8)));
typedef float f32x4 __attribute__((ext_vector_type(4)));
typedef _Float16 h2v __attribute__((ext_vector_type(2)));

// LDS row strides in BYTES (odd multiples of 16)
#define A1S 272   // A1: [16 rows][136 halfs]  k: 0..7 x | 8..107 h1 | pad
#define A2S 464   // A2: [16 rows][232 halfs]  k: 0..99 h1 | 100..199 h2 | pad
#define GSB 848   // G:  [16 rows][212 u32]    pair slot = type*52 + unit/2

// LDS arena carve-outs (role-disjoint code paths; 46.6KB < 64KB static limit)
//  L1: A1 [0,4352) | G [4352,17920) | XC [17920,26112) | H1S [26112,38912)
//  L2: A2 [0,7424) | G [7424,20992) | H1C [20992,46592)
#define L1_G   4352
#define L1_XC  17920
#define L1_H1S 26112
#define L2_G   7424
#define L2_H1C 20992

__device__ __forceinline__ unsigned packh2(float a, float b) {
    h2v p; p[0] = (_Float16)a; p[1] = (_Float16)b;
    return __builtin_bit_cast(unsigned, p);
}
__device__ __forceinline__ float2 unp(unsigned u) {
    h2v p = __builtin_bit_cast(h2v, u);
    return make_float2((float)p[0], (float)p[1]);
}
__device__ __forceinline__ float rcp_f(float x) {
#if __has_builtin(__builtin_amdgcn_rcpf)
    return __builtin_amdgcn_rcpf(x);
#else
    return 1.0f / x;
#endif
}
#define LOG2E 1.4426950408889634f
__device__ __forceinline__ float tanh_f(float x) {
    return fmaf(2.0f, rcp_f(1.0f + exp2f(-2.0f * LOG2E * x)), -1.0f);
}
__device__ __forceinline__ f32x4 mfma16(uint4 a, uint4 b, f32x4 c) {
    return __builtin_amdgcn_mfma_f32_16x16x32_f16(
        __builtin_bit_cast(f16x8, a), __builtin_bit_cast(f16x8, b), c, 0, 0, 0);
}

// Chunk-pipelined MFMA LSTM (R14 skeleton). grid 32 x 512.
//   blocks 0..15 : LAYER 1 on chunk ch;  blocks 16..31 : LAYER 2 on chunk ch-1.
// R15 change: h1 crosses layers in 4-STEP GROUPS staged through LDS.
//  - L1 update writes h1 to H1S (LDS); flushed to h1buf once per 4 steps.
//    The pre-barrier vmcnt(0) store-drain now costs 1/4 as often.
//  - L2 prefetches h1 groups into double-buffered H1C (LDS) 2 steps ahead;
//    the per-step h1 consumption is pure LDS (no exposed global latency).
// R14's per-step global h1 store+load inside the 2-barrier step structure was
// ~3000 of the 4260 cyc/step (vmcnt drain + load latency, both per-step).
__global__ __launch_bounds__(512, 1) void lstm_mfma_pipe(
    const float* __restrict__ x,
    const float* __restrict__ w_ih1, const float* __restrict__ w_hh1,
    const float* __restrict__ b_ih1, const float* __restrict__ b_hh1,
    const float* __restrict__ w_ih2, const float* __restrict__ w_hh2,
    const float* __restrict__ b_ih2, const float* __restrict__ b_hh2,
    unsigned* __restrict__ h1buf,   // [2][Tc][BB][50] packed f16x2
    float* __restrict__ c1s,        // [BB][HD]
    unsigned* __restrict__ h2sp,    // [BB][50] packed h2 state
    float* __restrict__ c2s,        // [BB][HD]
    float* __restrict__ h2f,        // [BB][HD] final h2 (f32)
    int Tc, int ch, int nch)
{
    const int role = blockIdx.x >> 4;
    const int b0   = (blockIdx.x & 15) * 16;
    const int tid  = threadIdx.x;
    const int lane = tid & 63;
    const int w    = tid >> 6;

    __shared__ __align__(16) char LB[46592];

    const int col = lane & 15, kg = lane >> 4;
    const int growb = (kg * 4) * GSB;

    const bool isUpd = tid < 208;
    const int  urow = tid & 15;
    const int  ub   = (tid >> 4) * 8;
    const int  gub  = urow * GSB + (ub >> 1) * 4;

    if (role == 0) {
        // ======================= LAYER 1, chunk ch =======================
        if (ch >= nch) return;
        const int t0 = ch * Tc, first = (ch == 0);
        const size_t bufC = (size_t)(ch & 1) * Tc * BB * 50;
        const size_t bufP = (size_t)((ch ^ 1) & 1) * Tc * BB * 50;
        const int a1base = col * A1S + kg * 16;
        const int T1 = 3 + (w == 5);
        char* Gb = LB + L1_G;
        unsigned* XCp = (unsigned*)(LB + L1_XC);     // [2][16][16][4]
        unsigned* H1S = (unsigned*)(LB + L1_H1S);    // [4][16][50] linear

        uint4 b1[4][4];
        float bias1v[4], am1[4], sc1[4], ad1[4]; int goff1[4];
        #pragma unroll
        for (int ti = 0; ti < 4; ++ti) if (ti < T1) {
            const int nn = (ti < 3) ? (ti * 8 + w) : 24;
            const int gate = nn * 16 + col;
            #pragma unroll
            for (int kt = 0; kt < 4; ++kt) {
                unsigned q[4];
                #pragma unroll
                for (int qq = 0; qq < 4; ++qq) {
                    const int ka = kt * 32 + kg * 8 + 2 * qq, kb = ka + 1;
                    float va = (ka < 8) ? w_ih1[gate * 8 + ka]
                             : (ka < 108 ? w_hh1[(size_t)gate * HD + ka - 8] : 0.f);
                    float vb = (kb < 8) ? w_ih1[gate * 8 + kb]
                             : (kb < 108 ? w_hh1[(size_t)gate * HD + kb - 8] : 0.f);
                    q[qq] = packh2(va, vb);
                }
                b1[ti][kt] = make_uint4(q[0], q[1], q[2], q[3]);
            }
            bias1v[ti] = b_ih1[gate] + b_hh1[gate];
            const bool tg = (gate >= 200) && (gate < 300);
            am1[ti] = tg ? 2.f : 1.f;
            sc1[ti] = tg ? (-2.f * LOG2E) : (-LOG2E);
            ad1[ti] = tg ? -1.f : 0.f;
            const int type = gate / 100, u = gate - type * 100;
            goff1[ti] = (type * 52 + (u >> 1)) * 4 + (u & 1) * 2;
        }

        float c1a[8] = {0,0,0,0,0,0,0,0};
        if (isUpd && !first) {
            #pragma unroll
            for (int q = 0; q < 4; ++q) {
                const int u0 = ub + 2 * q;
                if (u0 < 100) {
                    c1a[2*q]   = c1s[(b0 + urow) * HD + u0];
                    c1a[2*q+1] = c1s[(b0 + urow) * HD + u0 + 1];
                }
            }
        }

        for (int i = tid; i < 16 * (A1S / 4); i += 512) ((unsigned*)LB)[i] = 0u;
        for (int i = tid; i < 16 * (GSB / 4); i += 512) ((unsigned*)Gb)[i] = 0u;
        __syncthreads();     // zero-fill complete before staging (R13/R14 race fix)
        if (!first) {
            for (int i = tid; i < 800; i += 512) {
                const int row = i / 50, pr = i - row * 50;
                unsigned hp = h1buf[bufP + ((size_t)(Tc - 1) * BB + b0 + row) * 50 + pr];
                *(unsigned*)(LB + row * A1S + 16 + pr * 4) = hp;
            }
        }
        {   // stage x chunk 0
            const int s = (tid >> 5) & 15, xr = (tid >> 1) & 15, hq = tid & 1;
            float4 v = *(const float4*)(x + ((size_t)(b0 + xr) * TT + t0 + s) * 8 + hq * 4);
            XCp[((0 * 16 + s) * 16 + xr) * 4 + hq * 2]     = packh2(v.x, v.y);
            XCp[((0 * 16 + s) * 16 + xr) * 4 + hq * 2 + 1] = packh2(v.z, v.w);
        }
        __syncthreads();
        if (tid < 64) {
            const int xr = tid >> 2, q = tid & 3;
            *(unsigned*)(LB + xr * A1S + q * 4) = XCp[((0 * 16 + 0) * 16 + xr) * 4 + q];
        }
        __syncthreads();

        #pragma unroll 1
        for (int t = 0; t < Tc; ++t) {
            // --- grouped h1 copy-out (prev 4 steps), overlaps MFMA; drain 1/4 steps ---
            if ((t & 3) == 0 && t > 0) {
                const int tg = t - 4;
                for (int i = tid; i < 3200; i += 512) {
                    const int s = i / 800, rem = i - s * 800;
                    const int row = rem / 50, pr = rem - row * 50;
                    h1buf[bufC + ((size_t)(tg + s) * BB + b0 + row) * 50 + pr] = H1S[i];
                }
            }
            float4 xpf = {0.f, 0.f, 0.f, 0.f};
            const bool dopf = ((t & 15) == 14) && (t + 2 < Tc);
            const int  pfc = (t + 2) >> 4;
            const int  pfs = (tid >> 5) & 15, pfr = (tid >> 1) & 15, pfh = tid & 1;
            if (dopf)
                xpf = *(const float4*)(x + ((size_t)(b0 + pfr) * TT + t0 + pfc * 16 + pfs) * 8 + pfh * 4);

            // phase A: MFMA gates -> act -> G
            uint4 a1f[4];
            #pragma unroll
            for (int kt = 0; kt < 4; ++kt)
                a1f[kt] = *(const uint4*)((const char*)LB + a1base + kt * 64);
            #pragma unroll
            for (int ti = 0; ti < 4; ++ti) if (ti < T1) {
                f32x4 acc = {0.f, 0.f, 0.f, 0.f};
                #pragma unroll
                for (int kt = 0; kt < 4; ++kt) acc = mfma16(a1f[kt], b1[ti][kt], acc);
                #pragma unroll
                for (int j = 0; j < 4; ++j) {
                    float v = acc[j] + bias1v[ti];
                    float a = fmaf(am1[ti], rcp_f(1.f + exp2f(sc1[ti] * v)), ad1[ti]);
                    *(_Float16*)(Gb + growb + j * GSB + goff1[ti]) = (_Float16)a;
                }
            }
            __syncthreads();

            // phase B: update c1/h1 -> A1 + H1S (LDS, no global); x staging
            if (isUpd) {
                const char* gp = Gb + gub;
                uint4 pi = *(const uint4*)(gp);
                uint4 pf = *(const uint4*)(gp + 208);
                uint4 pg = *(const uint4*)(gp + 416);
                uint4 po = *(const uint4*)(gp + 624);
                unsigned ai[4] = {pi.x, pi.y, pi.z, pi.w};
                unsigned af[4] = {pf.x, pf.y, pf.z, pf.w};
                unsigned ag[4] = {pg.x, pg.y, pg.z, pg.w};
                unsigned ao[4] = {po.x, po.y, po.z, po.w};
                #pragma unroll
                for (int q = 0; q < 4; ++q) {
                    const int u0 = ub + 2 * q;
                    float2 vi = unp(ai[q]), vf = unp(af[q]), vg = unp(ag[q]), vo = unp(ao[q]);
                    c1a[2*q]   = vf.x * c1a[2*q]   + vi.x * vg.x;
                    c1a[2*q+1] = vf.y * c1a[2*q+1] + vi.y * vg.y;
                    float h0 = vo.x * tanh_f(c1a[2*q]);
                    float h1 = vo.y * tanh_f(c1a[2*q+1]);
                    if (u0 < 100) {
                        unsigned hp = packh2(h0, h1);
                        *(unsigned*)(LB + urow * A1S + 16 + u0 * 2) = hp;
                        H1S[((t & 3) * 16 + urow) * 50 + (ub >> 1) + q] = hp;
                        if (t == Tc - 1) {
                            c1s[(b0 + urow) * HD + u0]     = c1a[2*q];
                            c1s[(b0 + urow) * HD + u0 + 1] = c1a[2*q+1];
                        }
                    }
                }
            }
            if (dopf) {
                XCp[((((pfc & 1) * 16) + pfs) * 16 + pfr) * 4 + pfh * 2]     = packh2(xpf.x, xpf.y);
                XCp[((((pfc & 1) * 16) + pfs) * 16 + pfr) * 4 + pfh * 2 + 1] = packh2(xpf.z, xpf.w);
            }
            {
                const int nt = t + 1;
                if (nt < Tc && tid < 64) {
                    const int xr = tid >> 2, q = tid & 3;
                    *(unsigned*)(LB + xr * A1S + q * 4) =
                        XCp[((((nt >> 4) & 1) * 16 + (nt & 15)) * 16 + xr) * 4 + q];
                }
            }
            __syncthreads();
        }
        // flush last group
        {
            const int tg = Tc - 4;
            for (int i = tid; i < 3200; i += 512) {
                const int s = i / 800, rem = i - s * 800;
                const int row = rem / 50, pr = rem - row * 50;
                h1buf[bufC + ((size_t)(tg + s) * BB + b0 + row) * 50 + pr] = H1S[i];
            }
        }
    } else {
        // ======================= LAYER 2, chunk ch-1 =======================
        if (ch < 1) return;
        const int first = (ch == 1), last = (ch == nch);
        const unsigned* h1rd = h1buf + (size_t)((ch - 1) & 1) * Tc * BB * 50;
        const int a2base = col * A2S + kg * 16;
        const int T2 = 3 + (w == 4);
        char* Gb = LB + L2_G;
        unsigned* H1C = (unsigned*)(LB + L2_H1C);    // [2][4][16][50] linear per buf (3200 u32)

        uint4 b2[4][7];
        float bias2v[4], am2[4], sc2[4], ad2[4]; int goff2[4];
        #pragma unroll
        for (int ti = 0; ti < 4; ++ti) if (ti < T2) {
            const int nn = (ti < 3) ? (ti * 8 + w) : 24;
            const int gate = nn * 16 + col;
            #pragma unroll
            for (int kt = 0; kt < 7; ++kt) {
                unsigned q[4];
                #pragma unroll
                for (int qq = 0; qq < 4; ++qq) {
                    const int ka = kt * 32 + kg * 8 + 2 * qq, kb = ka + 1;
                    float va = (ka < 100) ? w_ih2[(size_t)gate * HD + ka]
                             : (ka < 200 ? w_hh2[(size_t)gate * HD + ka - 100] : 0.f);
                    float vb = (kb < 100) ? w_ih2[(size_t)gate * HD + kb]
                             : (kb < 200 ? w_hh2[(size_t)gate * HD + kb - 100] : 0.f);
                    q[qq] = packh2(va, vb);
                }
                b2[ti][kt] = make_uint4(q[0], q[1], q[2], q[3]);
            }
            bias2v[ti] = b_ih2[gate] + b_hh2[gate];
            const bool tg = (gate >= 200) && (gate < 300);
            am2[ti] = tg ? 2.f : 1.f;
            sc2[ti] = tg ? (-2.f * LOG2E) : (-LOG2E);
            ad2[ti] = tg ? -1.f : 0.f;
            const int type = gate / 100, u = gate - type * 100;
            goff2[ti] = (type * 52 + (u >> 1)) * 4 + (u & 1) * 2;
        }

        float c2a[8] = {0,0,0,0,0,0,0,0};
        if (isUpd && !first) {
            #pragma unroll
            for (int q = 0; q < 4; ++q) {
                const int u0 = ub + 2 * q;
                if (u0 < 100) {
                    c2a[2*q]   = c2s[(b0 + urow) * HD + u0];
                    c2a[2*q+1] = c2s[(b0 + urow) * HD + u0 + 1];
                }
            }
        }

        for (int i = tid; i < 16 * (A2S / 4); i += 512) ((unsigned*)LB)[i] = 0u;
        for (int i = tid; i < 16 * (GSB / 4); i += 512) ((unsigned*)Gb)[i] = 0u;
        // pre-stage h1 group 0 into H1C[0]
        #pragma unroll
        for (int j = 0; j < 7; ++j) {
            const int i = tid + j * 512;
            if (i < 3200) {
                const int s = i / 800, rem = i - s * 800;
                const int row = rem / 50, pr = rem - row * 50;
                H1C[i] = h1rd[((size_t)s * BB + b0 + row) * 50 + pr];
            }
        }
        __syncthreads();     // zero-fill + H1C[0] complete
        {   // A2 k0..99 <- h1(step 0);  A2 k100..199 <- h2 state
            const int i0 = tid;
            if (i0 < 800) { const int r = i0 / 50, pr = i0 - r * 50;
                *(unsigned*)(LB + r * A2S + pr * 4) = H1C[i0]; }
            const int i1 = tid + 512;
            if (i1 < 800) { const int r = i1 / 50, pr = i1 - r * 50;
                *(unsigned*)(LB + r * A2S + pr * 4) = H1C[i1]; }
            if (!first) {
                for (int i = tid; i < 800; i += 512) {
                    const int row = i / 50, pr = i - row * 50;
                    *(unsigned*)(LB + row * A2S + 200 + pr * 4) =
                        h2sp[(size_t)(b0 + row) * 50 + pr];
                }
            }
        }
        __syncthreads();

        unsigned preg[7] = {0,0,0,0,0,0,0};
        #pragma unroll 1
        for (int t = 0; t < Tc; ++t) {
            const int g = t >> 2;
            const bool pfg = ((t & 3) == 0) && (g + 1 < (Tc >> 2));
            if (pfg) {   // issue group g+1 loads (land 2 steps later)
                #pragma unroll
                for (int j = 0; j < 7; ++j) {
                    const int i = tid + j * 512;
                    if (i < 3200) {
                        const int s = i / 800, rem = i - s * 800;
                        const int row = rem / 50, pr = rem - row * 50;
                        preg[j] = h1rd[((size_t)((g + 1) * 4 + s) * BB + b0 + row) * 50 + pr];
                    }
                }
            }

            // phase C: MFMA gates -> act -> G
            uint4 a2f[7];
            #pragma unroll
            for (int kt = 0; kt < 7; ++kt)
                a2f[kt] = *(const uint4*)((const char*)LB + a2base + kt * 64);
            #pragma unroll
            for (int ti = 0; ti < 4; ++ti) if (ti < T2) {
                f32x4 acc = {0.f, 0.f, 0.f, 0.f};
                #pragma unroll
                for (int kt = 0; kt < 7; ++kt) acc = mfma16(a2f[kt], b2[ti][kt], acc);
                #pragma unroll
                for (int j = 0; j < 4; ++j) {
                    float v = acc[j] + bias2v[ti];
                    float a = fmaf(am2[ti], rcp_f(1.f + exp2f(sc2[ti] * v)), ad2[ti]);
                    *(_Float16*)(Gb + growb + j * GSB + goff2[ti]) = (_Float16)a;
                }
            }
            __syncthreads();

            // phase D: update c2/h2 -> A2 k100..; h1(t+1) LDS->LDS; H1C landing
            if (isUpd) {
                const char* gp = Gb + gub;
                uint4 pi = *(const uint4*)(gp);
                uint4 pf = *(const uint4*)(gp + 208);
                uint4 pg = *(const uint4*)(gp + 416);
                uint4 po = *(const uint4*)(gp + 624);
                unsigned ai[4] = {pi.x, pi.y, pi.z, pi.w};
                unsigned af[4] = {pf.x, pf.y, pf.z, pf.w};
                unsigned ag[4] = {pg.x, pg.y, pg.z, pg.w};
                unsigned ao[4] = {po.x, po.y, po.z, po.w};
                #pragma unroll
                for (int q = 0; q < 4; ++q) {
                    const int u0 = ub + 2 * q;
                    float2 vi = unp(ai[q]), vf = unp(af[q]), vg = unp(ag[q]), vo = unp(ao[q]);
                    c2a[2*q]   = vf.x * c2a[2*q]   + vi.x * vg.x;
                    c2a[2*q+1] = vf.y * c2a[2*q+1] + vi.y * vg.y;
                    float h0 = vo.x * tanh_f(c2a[2*q]);
                    float h1 = vo.y * tanh_f(c2a[2*q+1]);
                    if (u0 < 100) {
                        unsigned hp = packh2(h0, h1);
                        *(unsigned*)(LB + urow * A2S + 200 + u0 * 2) = hp;
                        if (t == Tc - 1) {
                            h2sp[(size_t)(b0 + urow) * 50 + (ub >> 1) + q] = hp;
                            c2s[(b0 + urow) * HD + u0]     = c2a[2*q];
                            c2s[(b0 + urow) * HD + u0 + 1] = c2a[2*q+1];
                            if (last) {
                                h2f[(size_t)(b0 + urow) * HD + u0]     = h0;
                                h2f[(size_t)(b0 + urow) * HD + u0 + 1] = h1;
                            }
                        }
                    }
                }
            }
            if ((t & 3) == 2 && (g + 1 < (Tc >> 2))) {   // land prefetched group
                unsigned* dst = H1C + ((g + 1) & 1) * 3200;
                #pragma unroll
                for (int j = 0; j < 7; ++j) {
                    const int i = tid + j * 512;
                    if (i < 3200) dst[i] = preg[j];
                }
            }
            if (t + 1 < Tc) {   // A2 k0..99 <- h1(t+1) from H1C (pure LDS)
                const int nt = t + 1;
                const unsigned* src = H1C + ((nt >> 2) & 1) * 3200 + (nt & 3) * 800;
                const int i0 = tid;
                if (i0 < 800) { const int r = i0 / 50, pr = i0 - r * 50;
                    *(unsigned*)(LB + r * A2S + pr * 4) = src[i0]; }
                const int i1 = tid + 512;
                if (i1 < 800) { const int r = i1 / 50, pr = i1 - r * 50;
                    *(unsigned*)(LB + r * A2S + pr * 4) = src[i1]; }
            }
            __syncthreads();
        }
    }
}

// ---------------- FC head ----------------
__global__ void fc_head(const float* __restrict__ h2,
                        const float* __restrict__ fc1_w, const float* __restrict__ fc1_b,
                        const float* __restrict__ fc2_w, const float* __restrict__ fc2_b,
                        float* __restrict__ out)
{
    const int bidx = threadIdx.x;
    const float* h = h2 + (size_t)bidx * HD;
    float hv[HD];
    #pragma unroll
    for (int kk = 0; kk < HD / 4; ++kk) {
        float4 v = *(const float4*)(h + 4 * kk);
        hv[4*kk+0] = v.x; hv[4*kk+1] = v.y; hv[4*kk+2] = v.z; hv[4*kk+3] = v.w;
    }
    float y = fc2_b[0];
    #pragma unroll
    for (int m = 0; m < 25; ++m) {
        float a = fc1_b[m];
        const float* wp = fc1_w + m * HD;
        #pragma unroll
        for (int k = 0; k < HD; ++k) a += hv[k] * wp[k];
        y += a * fc2_w[m];
    }
    out[bidx] = y;
}

extern "C" void kernel_launch(void* const* d_in, const int* in_sizes, int n_in,
                              void* d_out, int out_size, void* d_ws, size_t ws_size,
                              hipStream_t stream) {
    const float* x     = (const float*)d_in[0];
    const float* w_ih1 = (const float*)d_in[1];
    const float* w_hh1 = (const float*)d_in[2];
    const float* b_ih1 = (const float*)d_in[3];
    const float* b_hh1 = (const float*)d_in[4];
    const float* w_ih2 = (const float*)d_in[5];
    const float* w_hh2 = (const float*)d_in[6];
    const float* b_ih2 = (const float*)d_in[7];
    const float* b_hh2 = (const float*)d_in[8];
    const float* fc1_w = (const float*)d_in[9];
    const float* fc1_b = (const float*)d_in[10];
    const float* fc2_w = (const float*)d_in[11];
    const float* fc2_b = (const float*)d_in[12];
    float* out = (float*)d_out;

    int Tc = 256;  // multiple of 16, divides TT
    while (Tc > 16 &&
           2 * (size_t)Tc * BB * 50 * 4 + (size_t)BB * (HD * 3 + 50) * 4 > ws_size)
        Tc >>= 1;
    const int nch = TT / Tc;

    unsigned* h1buf = (unsigned*)d_ws;                      // [2][Tc][BB][50]
    float* c1s = (float*)(h1buf + 2 * (size_t)Tc * BB * 50);
    float* c2s = c1s + (size_t)BB * HD;
    float* h2f = c2s + (size_t)BB * HD;
    unsigned* h2sp = (unsigned*)(h2f + (size_t)BB * HD);

    for (int ch = 0; ch <= nch; ++ch) {
        lstm_mfma_pipe<<<32, 512, 0, stream>>>(x, w_ih1, w_hh1, b_ih1, b_hh1,
                                               w_ih2, w_hh2, b_ih2, b_hh2,
                                               h1buf, c1s, h2sp, c2s, h2f,
                                               Tc, ch, nch);
    }
    fc_head<<<1, 256, 0, stream>>>(h2f, fc1_w, fc1_b, fc2_w, fc2_b, out);
}

// Round 16
// 3186.282 us; speedup vs baseline: 1.4083x; 1.4083x over previous
//
#include <hip/hip_runtime.h>

#define BB 256
#define TT 2048
#define HD 100

typedef _Float16 h2v __attribute__((ext_vector_type(2)));
typedef _Float16 f16x8 __attribute__((ext_vector_type(8)));
typedef float f32x4 __attribute__((ext_vector_type(4)));

__device__ __forceinline__ float fdot2(unsigned w, unsigned h, float c) {
#if __has_builtin(__builtin_amdgcn_fdot2)
    return __builtin_amdgcn_fdot2(__builtin_bit_cast(h2v, w),
                                  __builtin_bit_cast(h2v, h), c, false);
#else
    h2v a = __builtin_bit_cast(h2v, w), b = __builtin_bit_cast(h2v, h);
    c = fmaf((float)a[0], (float)b[0], c);
    c = fmaf((float)a[1], (float)b[1], c);
    return c;
#endif
}
__device__ __forceinline__ unsigned packh2(float a, float b) {
    h2v p; p[0] = (_Float16)a; p[1] = (_Float16)b;
    return __builtin_bit_cast(unsigned, p);
}
__device__ __forceinline__ float rcp_f(float x) {
#if __has_builtin(__builtin_amdgcn_rcpf)
    return __builtin_amdgcn_rcpf(x);
#else
    return 1.0f / x;
#endif
}
__device__ __forceinline__ float sigmoid_f(float x) { return rcp_f(1.0f + __expf(-x)); }
__device__ __forceinline__ float tanh_f(float x) {
    return fmaf(2.0f, rcp_f(1.0f + __expf(-2.0f * x)), -1.0f);
}
__device__ __forceinline__ f32x4 mfma16(uint4 a, uint4 b, f32x4 c) {
    return __builtin_amdgcn_mfma_f32_16x16x32_f16(
        __builtin_bit_cast(f16x8, a), __builtin_bit_cast(f16x8, b), c, 0, 0, 0);
}

// =================== A: recurrence pair (one launch per chunk) ==============
// grid 512 x 256 threads (4 waves -> the PROVEN-CLEAN register regime: R6/R12
// measured 208-216 arch VGPRs, zero scratch).
//   blocks 0..255  : LAYER-1 recurrence on chunk ch (row b) — verbatim R6-l1.
//   blocks 256..511: LAYER-2 recurrence on chunk ch-1 (row b) — h2-projection
//                    ONLY (w_hh2, 100 u32/thread); the input projection
//                    xg2 = h1.w_ih2^T + biases is PRECOMPUTED by the G kernel
//                    and prefetched here in 8-step groups into LDS, so no
//                    per-step global access sits on the critical path
//                    (R12's failure mode).
// readlane ignores EXEC: gate compute is branchless over all 256 threads with
// clamped row ids; only stores are role-guarded (R5 lesson).
__global__ __launch_bounds__(256, 1) void lstm_rec(
    const float* __restrict__ x,
    const float* __restrict__ w_ih1, const float* __restrict__ w_hh1,
    const float* __restrict__ b_ih1, const float* __restrict__ b_hh1,
    const float* __restrict__ w_hh2,
    const float* __restrict__ xg2,   // [Tc*256][400] fp32
    unsigned* __restrict__ h1buf,    // [Tc*256][52] u32 packed f16x2 (+64 slack)
    float* __restrict__ c1s,         // [256][100]
    unsigned* __restrict__ h2sp,     // [256][50]
    float* __restrict__ c2s,         // [256][100]
    float* __restrict__ h2f,         // [256][100]
    int Tc, int ch, int nch)
{
    const int role = blockIdx.x >> 8;
    const int b    = blockIdx.x & 255;
    const int tid  = threadIdx.x, lane = tid & 63;

    __shared__ unsigned hsp[64];
    __shared__ float glds[400];
    __shared__ unsigned xs[2][32][4];
    __shared__ float XG[2][8][400];

    const bool isG = tid < 200;
    const int  gt  = isG ? tid : 199;
    const int  um  = tid >> 2;
    const bool isU = ((tid & 3) == 3) && (tid < 200);   // um in 0..49
    const int  g0 = 2 * gt, g1r = 2 * gt + 1;
    const bool tg = (gt >= 100) && (gt < 150);          // rows 200..299 = g gate

    if (role == 0) {
        // ----------------- LAYER 1 recurrence, chunk ch -----------------
        if (ch >= nch) return;
        const int t0 = ch * Tc, first = (ch == 0);
        const bool isX = ((tid & 3) == 1) && (tid < 128);   // um in 0..31

        unsigned wA[54], wB[54];
        float bias0, bias1, cc0 = 0.f, cc1 = 0.f;
        { const float4* p = (const float4*)(w_ih1 + (size_t)g0 * 8);
          float4 v0 = p[0], v1 = p[1];
          wA[0] = packh2(v0.x, v0.y); wA[1] = packh2(v0.z, v0.w);
          wA[2] = packh2(v1.x, v1.y); wA[3] = packh2(v1.z, v1.w); }
        { const float4* p = (const float4*)(w_ih1 + (size_t)g1r * 8);
          float4 v0 = p[0], v1 = p[1];
          wB[0] = packh2(v0.x, v0.y); wB[1] = packh2(v0.z, v0.w);
          wB[2] = packh2(v1.x, v1.y); wB[3] = packh2(v1.z, v1.w); }
        { const float4* p = (const float4*)(w_hh1 + (size_t)g0 * HD);
          #pragma unroll
          for (int q = 0; q < 25; ++q) { float4 v = p[q];
              wA[4 + 2*q] = packh2(v.x, v.y); wA[5 + 2*q] = packh2(v.z, v.w); } }
        { const float4* p = (const float4*)(w_hh1 + (size_t)g1r * HD);
          #pragma unroll
          for (int q = 0; q < 25; ++q) { float4 v = p[q];
              wB[4 + 2*q] = packh2(v.x, v.y); wB[5 + 2*q] = packh2(v.z, v.w); } }
        bias0 = b_ih1[g0] + b_hh1[g0];
        bias1 = b_ih1[g1r] + b_hh1[g1r];

        if (isU && !first) {
            cc0 = c1s[b * HD + 2 * um];
            cc1 = c1s[b * HD + 2 * um + 1];
        }
        if (tid < 64) {
            unsigned v = 0u;
            if (!first && tid < 50)
                v = h1buf[((size_t)(Tc - 1) * BB + b) * 52 + tid];
            hsp[tid] = v;
        }
        if (isX) {
            const int s = um;
            const float4* p = (const float4*)(x + ((size_t)b * TT + t0 + s) * 8);
            float4 v0 = p[0], v1 = p[1];
            xs[0][s][0] = packh2(v0.x, v0.y); xs[0][s][1] = packh2(v0.z, v0.w);
            xs[0][s][2] = packh2(v1.x, v1.y); xs[0][s][3] = packh2(v1.z, v1.w);
        }
        __syncthreads();

        float4 pa = {0,0,0,0}, pb = {0,0,0,0};
        #pragma unroll 1
        for (int t = 0; t < Tc; ++t) {
            const bool pf = ((t & 31) == 0) && (t + 32 < Tc) && isX;
            if (pf) {
                const float4* p = (const float4*)(x + ((size_t)b * TT + t0 + t + 32 + um) * 8);
                pa = p[0]; pb = p[1];
            }
            const unsigned st = hsp[lane];                 // exec-full load
            const unsigned* xq = xs[(t >> 5) & 1][t & 31];
            unsigned x0 = xq[0], x1 = xq[1], x2 = xq[2], x3 = xq[3];
            float a0 = bias0, a1 = bias1, a2 = 0.f, a3 = 0.f;
            a0 = fdot2(wA[0], x0, a0); a1 = fdot2(wB[0], x0, a1);
            a2 = fdot2(wA[1], x1, a2); a3 = fdot2(wB[1], x1, a3);
            a0 = fdot2(wA[2], x2, a0); a1 = fdot2(wB[2], x2, a1);
            a2 = fdot2(wA[3], x3, a2); a3 = fdot2(wB[3], x3, a3);
            #pragma unroll
            for (int k = 0; k < 50; ++k) {
                unsigned hk = (unsigned)__builtin_amdgcn_readlane((int)st, k);
                if (k & 1) { a2 = fdot2(wA[4 + k], hk, a2); a3 = fdot2(wB[4 + k], hk, a3); }
                else       { a0 = fdot2(wA[4 + k], hk, a0); a1 = fdot2(wB[4 + k], hk, a1); }
            }
            float r0 = a0 + a2, r1 = a1 + a3;
            r0 = tg ? tanh_f(r0) : sigmoid_f(r0);
            r1 = tg ? tanh_f(r1) : sigmoid_f(r1);
            if (isG) *(float2*)(glds + 2 * tid) = make_float2(r0, r1);
            __syncthreads();
            if (isU) {
                const int j = 2 * um;
                float2 gi = *(const float2*)(glds + j);
                float2 gf = *(const float2*)(glds + 100 + j);
                float2 gg = *(const float2*)(glds + 200 + j);
                float2 go = *(const float2*)(glds + 300 + j);
                cc0 = gf.x * cc0 + gi.x * gg.x;
                cc1 = gf.y * cc1 + gi.y * gg.y;
                float h0 = go.x * tanh_f(cc0);
                float h1v = go.y * tanh_f(cc1);
                unsigned hp = packh2(h0, h1v);
                hsp[um] = hp;
                h1buf[((size_t)t * BB + b) * 52 + um] = hp;
                if (t == Tc - 1) { c1s[b * HD + j] = cc0; c1s[b * HD + j + 1] = cc1; }
            }
            if (pf) {
                const int nb2 = ((t >> 5) + 1) & 1; const int s = um;
                xs[nb2][s][0] = packh2(pa.x, pa.y); xs[nb2][s][1] = packh2(pa.z, pa.w);
                xs[nb2][s][2] = packh2(pb.x, pb.y); xs[nb2][s][3] = packh2(pb.z, pb.w);
            }
            __syncthreads();
        }
    } else {
        // ----------------- LAYER 2 recurrence, chunk ch-1 -----------------
        if (ch < 1) return;
        const int first = (ch == 1), last = (ch == nch);

        unsigned wHA[50], wHB[50];
        float cc0 = 0.f, cc1 = 0.f;
        { const float4* p = (const float4*)(w_hh2 + (size_t)g0 * HD);
          #pragma unroll
          for (int q = 0; q < 25; ++q) { float4 v = p[q];
              wHA[2*q] = packh2(v.x, v.y); wHA[2*q+1] = packh2(v.z, v.w); } }
        { const float4* p = (const float4*)(w_hh2 + (size_t)g1r * HD);
          #pragma unroll
          for (int q = 0; q < 25; ++q) { float4 v = p[q];
              wHB[2*q] = packh2(v.x, v.y); wHB[2*q+1] = packh2(v.z, v.w); } }

        if (isU && !first) {
            cc0 = c2s[b * HD + 2 * um];
            cc1 = c2s[b * HD + 2 * um + 1];
        }
        if (tid < 64) {
            unsigned v = 0u;
            if (!first && tid < 50) v = h2sp[b * 50 + tid];
            hsp[tid] = v;
        }
        // preload xg2 group 0 (steps 0..7) into XG[0]
        #pragma unroll
        for (int j = 0; j < 4; ++j) {
            const int idx = tid + j * 256;          // float4 index, 800 total
            if (idx < 800) {
                const int s = idx / 100, n4 = idx - s * 100;
                *(float4*)&XG[0][s][n4 * 4] =
                    *(const float4*)&xg2[(((size_t)s * BB) + b) * 400 + n4 * 4];
            }
        }
        __syncthreads();

        float4 pre[4];
        #pragma unroll 1
        for (int t = 0; t < Tc; ++t) {
            const int g = t >> 3;
            const bool pfg = ((t & 7) == 0) && ((g + 1) * 8 < Tc);
            if (pfg) {   // issue next-group loads; land at t+4 (huge slack)
                #pragma unroll
                for (int j = 0; j < 4; ++j) {
                    const int idx = tid + j * 256;
                    if (idx < 800) {
                        const int s = idx / 100, n4 = idx - s * 100;
                        pre[j] = *(const float4*)
                            &xg2[(((size_t)((g + 1) * 8 + s) * BB) + b) * 400 + n4 * 4];
                    }
                }
            }
            const unsigned st2 = hsp[lane];                 // exec-full
            const float2 xg = *(const float2*)&XG[g & 1][t & 7][2 * gt];
            float a0 = xg.x, a1 = xg.y, a2 = 0.f, a3 = 0.f;
            #pragma unroll
            for (int k = 0; k < 50; ++k) {
                unsigned hk = (unsigned)__builtin_amdgcn_readlane((int)st2, k);
                if (k & 1) { a2 = fdot2(wHA[k], hk, a2); a3 = fdot2(wHB[k], hk, a3); }
                else       { a0 = fdot2(wHA[k], hk, a0); a1 = fdot2(wHB[k], hk, a1); }
            }
            float r0 = a0 + a2, r1 = a1 + a3;
            r0 = tg ? tanh_f(r0) : sigmoid_f(r0);
            r1 = tg ? tanh_f(r1) : sigmoid_f(r1);
            if (isG) *(float2*)(glds + 2 * tid) = make_float2(r0, r1);
            __syncthreads();
            if ((t & 7) == 4 && ((g + 1) * 8 < Tc)) {       // land group g+1
                #pragma unroll
                for (int j = 0; j < 4; ++j) {
                    const int idx = tid + j * 256;
                    if (idx < 800) {
                        const int s = idx / 100, n4 = idx - s * 100;
                        *(float4*)&XG[(g + 1) & 1][s][n4 * 4] = pre[j];
                    }
                }
            }
            if (isU) {
                const int j = 2 * um;
                float2 gi = *(const float2*)(glds + j);
                float2 gf = *(const float2*)(glds + 100 + j);
                float2 gg = *(const float2*)(glds + 200 + j);
                float2 go = *(const float2*)(glds + 300 + j);
                cc0 = gf.x * cc0 + gi.x * gg.x;
                cc1 = gf.y * cc1 + gi.y * gg.y;
                float h0 = go.x * tanh_f(cc0);
                float h1v = go.y * tanh_f(cc1);
                hsp[um] = packh2(h0, h1v);
                if (t == Tc - 1) {
                    h2sp[b * 50 + um] = packh2(h0, h1v);
                    c2s[b * HD + j] = cc0; c2s[b * HD + j + 1] = cc1;
                    if (last) { h2f[b * HD + j] = h0; h2f[b * HD + j + 1] = h1v; }
                }
            }
            __syncthreads();
        }
    }
}

// =================== G: xg2 = h1 . w_ih2^T + biases (MFMA GEMM) =============
// M = Tc*256 rows (r = t*256+b), N = 400 gates, K = 100 (padded to 128 with
// B-zeros so A can read garbage). Fragment mappings verbatim from R13/R14
// (correctness-verified): A row=l&15 k=(l>>4)*8+i; B col=l&15 same k;
// C col=l&15 row=(l>>4)*4+j. One 16x16 tile per wave, 4 waves/block.
__global__ __launch_bounds__(256, 1) void xg2_gemm(
    const unsigned* __restrict__ h1buf,  // [M][52] u32 (+slack)
    const float* __restrict__ w_ih2,     // [400][100] f32
    const float* __restrict__ b_ih2, const float* __restrict__ b_hh2,
    float* __restrict__ xg2,             // [M][400] f32
    int Mrows)
{
    const int tid = threadIdx.x, lane = tid & 63, w = tid >> 6;
    const int W  = blockIdx.x * 4 + w;
    const int mt = W / 25, nt = W - mt * 25;
    if (mt * 16 >= Mrows) return;
    const int col = lane & 15, kg = lane >> 4;
    const int r    = mt * 16 + col;
    const int gate = nt * 16 + col;

    uint4 a[4];
    #pragma unroll
    for (int kt = 0; kt < 4; ++kt)
        a[kt] = *(const uint4*)&h1buf[(size_t)r * 52 + kt * 16 + kg * 4];

    uint4 bf[4];
    #pragma unroll
    for (int kt = 0; kt < 3; ++kt) {
        const float4 va = *(const float4*)&w_ih2[(size_t)gate * HD + kt * 32 + kg * 8];
        const float4 vb = *(const float4*)&w_ih2[(size_t)gate * HD + kt * 32 + kg * 8 + 4];
        bf[kt] = make_uint4(packh2(va.x, va.y), packh2(va.z, va.w),
                            packh2(vb.x, vb.y), packh2(vb.z, vb.w));
    }
    {   // kt=3: k = 96..127 -> only kg==0 has real k (96..99)
        if (kg == 0) {
            const float4 va = *(const float4*)&w_ih2[(size_t)gate * HD + 96];
            bf[3] = make_uint4(packh2(va.x, va.y), packh2(va.z, va.w), 0u, 0u);
        } else {
            bf[3] = make_uint4(0u, 0u, 0u, 0u);
        }
    }

    f32x4 acc = {0.f, 0.f, 0.f, 0.f};
    #pragma unroll
    for (int kt = 0; kt < 4; ++kt) acc = mfma16(a[kt], bf[kt], acc);

    const float bias = b_ih2[gate] + b_hh2[gate];
    #pragma unroll
    for (int j = 0; j < 4; ++j)
        xg2[((size_t)mt * 16 + kg * 4 + j) * 400 + gate] = acc[j] + bias;
}

// ---------------- FC head ----------------
__global__ void fc_head(const float* __restrict__ h2,
                        const float* __restrict__ fc1_w, const float* __restrict__ fc1_b,
                        const float* __restrict__ fc2_w, const float* __restrict__ fc2_b,
                        float* __restrict__ out)
{
    const int bidx = threadIdx.x;
    const float* h = h2 + (size_t)bidx * HD;
    float hv[HD];
    #pragma unroll
    for (int kk = 0; kk < HD / 4; ++kk) {
        float4 v = *(const float4*)(h + 4 * kk);
        hv[4*kk+0] = v.x; hv[4*kk+1] = v.y; hv[4*kk+2] = v.z; hv[4*kk+3] = v.w;
    }
    float y = fc2_b[0];
    #pragma unroll
    for (int m = 0; m < 25; ++m) {
        float a = fc1_b[m];
        const float* wp = fc1_w + m * HD;
        #pragma unroll
        for (int k = 0; k < HD; ++k) a += hv[k] * wp[k];
        y += a * fc2_w[m];
    }
    out[bidx] = y;
}

extern "C" void kernel_launch(void* const* d_in, const int* in_sizes, int n_in,
                              void* d_out, int out_size, void* d_ws, size_t ws_size,
                              hipStream_t stream) {
    const float* x     = (const float*)d_in[0];
    const float* w_ih1 = (const float*)d_in[1];
    const float* w_hh1 = (const float*)d_in[2];
    const float* b_ih1 = (const float*)d_in[3];
    const float* b_hh1 = (const float*)d_in[4];
    const float* w_ih2 = (const float*)d_in[5];
    const float* w_hh2 = (const float*)d_in[6];
    const float* b_ih2 = (const float*)d_in[7];
    const float* b_hh2 = (const float*)d_in[8];
    const float* fc1_w = (const float*)d_in[9];
    const float* fc1_b = (const float*)d_in[10];
    const float* fc2_w = (const float*)d_in[11];
    const float* fc2_b = (const float*)d_in[12];
    float* out = (float*)d_out;

    // Tc: multiple of 8, divides TT; sized so ws fits xg2 + h1buf + states.
    int Tc = 128;
    auto need = [](int tc) -> size_t {
        return (size_t)tc * BB * 400 * 4                 // xg2 fp32
             + ((size_t)tc * BB * 52 + 64) * 4           // h1buf + slack
             + (size_t)BB * (HD * 3 + 50) * 4;           // c1s,c2s,h2f,h2sp
    };
    while (Tc > 16 && need(Tc) > ws_size) Tc >>= 1;
    const int nch = TT / Tc;
    const int Mrows = Tc * BB;

    float* xg2 = (float*)d_ws;
    unsigned* h1buf = (unsigned*)(xg2 + (size_t)Mrows * 400);
    float* c1s = (float*)(h1buf + (size_t)Mrows * 52 + 64);
    float* c2s = c1s + (size_t)BB * HD;
    float* h2f = c2s + (size_t)BB * HD;
    unsigned* h2sp = (unsigned*)(h2f + (size_t)BB * HD);

    const int gblocks = (Mrows / 16) * 25 / 4;   // Mtiles*25 waves, 4 waves/block

    for (int ch = 0; ch < nch; ++ch) {
        lstm_rec<<<512, 256, 0, stream>>>(x, w_ih1, w_hh1, b_ih1, b_hh1, w_hh2,
                                          xg2, h1buf, c1s, h2sp, c2s, h2f,
                                          Tc, ch, nch);
        xg2_gemm<<<gblocks, 256, 0, stream>>>(h1buf, w_ih2, b_ih2, b_hh2,
                                              xg2, Mrows);
    }
    lstm_rec<<<512, 256, 0, stream>>>(x, w_ih1, w_hh1, b_ih1, b_hh1, w_hh2,
                                      xg2, h1buf, c1s, h2sp, c2s, h2f,
                                      Tc, nch, nch);
    fc_head<<<1, 256, 0, stream>>>(h2f, fc1_w, fc1_b, fc2_w, fc2_b, out);
}

// Round 17
// 3078.414 us; speedup vs baseline: 1.4577x; 1.0350x over previous
//
#include <hip/hip_runtime.h>

#define BB 256
#define TT 2048
#define HD 100

typedef _Float16 h2v __attribute__((ext_vector_type(2)));
typedef _Float16 f16x8 __attribute__((ext_vector_type(8)));
typedef float f32x4 __attribute__((ext_vector_type(4)));

// shared arena offsets (bytes); role-disjoint regions overlap.
//  common: glds[2][400] f32             [0, 3200)
//  role0 : xs[2][32][4] u32             [3200, 4224)
//          H1R[16][52] u32              [4224, 7552)
//  role1 : XG[2][8][400] f32            [3200, 28800)
#define OFF_XS  3200
#define OFF_H1R 4224
#define OFF_XG  3200
#define ARENA   28800

__device__ __forceinline__ float fdot2(unsigned w, unsigned h, float c) {
#if __has_builtin(__builtin_amdgcn_fdot2)
    return __builtin_amdgcn_fdot2(__builtin_bit_cast(h2v, w),
                                  __builtin_bit_cast(h2v, h), c, false);
#else
    h2v a = __builtin_bit_cast(h2v, w), b = __builtin_bit_cast(h2v, h);
    c = fmaf((float)a[0], (float)b[0], c);
    c = fmaf((float)a[1], (float)b[1], c);
    return c;
#endif
}
__device__ __forceinline__ unsigned packh2(float a, float b) {
    h2v p; p[0] = (_Float16)a; p[1] = (_Float16)b;
    return __builtin_bit_cast(unsigned, p);
}
__device__ __forceinline__ float rcp_f(float x) {
#if __has_builtin(__builtin_amdgcn_rcpf)
    return __builtin_amdgcn_rcpf(x);
#else
    return 1.0f / x;
#endif
}
__device__ __forceinline__ float sigmoid_f(float x) { return rcp_f(1.0f + __expf(-x)); }
__device__ __forceinline__ float tanh_f(float x) {
    return fmaf(2.0f, rcp_f(1.0f + __expf(-2.0f * x)), -1.0f);
}
__device__ __forceinline__ f32x4 mfma16(uint4 a, uint4 b, f32x4 c) {
    return __builtin_amdgcn_mfma_f32_16x16x32_f16(
        __builtin_bit_cast(f16x8, a), __builtin_bit_cast(f16x8, b), c, 0, 0, 0);
}

// ============ A: recurrence pair, ONE barrier per step ============
// grid 512 x 256 threads. blocks 0..255: L1 chunk ch; 256..511: L2 chunk ch-1.
// R17 structure (vs R16):
//  - c/h state REPLICATED in registers per wave (lanes 0..49 hold pair `lane`);
//    ALL 4 waves recompute the update from gate LDS. readlane source is the
//    wave's own register -> no loop-head ds_read; exec-full by construction
//    (lanes 0..49 always execute the update; readlane only reads lanes <50).
//  - ONE __syncthreads per step: gates double-buffered glds[t&1]
//    (write bf | BAR | read bf; next write hits bf^1 -> race-free).
//  - L1 h1 -> 16-slot LDS ring, flushed to global every 8 steps (flush of a
//    group happens >=4 barriers after its last ring write). 7/8 barriers have
//    no outstanding VMEM -> no vmcnt(0) drain.
//  - L2 xg2 group prefetch issued right AFTER the barrier (full-step slack).
__global__ __launch_bounds__(256, 1) void lstm_rec(
    const float* __restrict__ x,
    const float* __restrict__ w_ih1, const float* __restrict__ w_hh1,
    const float* __restrict__ b_ih1, const float* __restrict__ b_hh1,
    const float* __restrict__ w_hh2,
    const float* __restrict__ xg2,   // [Tc*256][400] fp32
    unsigned* __restrict__ h1buf,    // [Tc*256][52] u32 packed f16x2 (+slack)
    float* __restrict__ c1s,         // [256][100]
    unsigned* __restrict__ h2sp,     // [256][50]
    float* __restrict__ c2s,         // [256][100]
    float* __restrict__ h2f,         // [256][100]
    int Tc, int ch, int nch)
{
    const int role = blockIdx.x >> 8;
    const int b    = blockIdx.x & 255;
    const int tid  = threadIdx.x, lane = tid & 63, w = tid >> 6;

    __shared__ __align__(16) char LB[ARENA];
    float* glds = (float*)LB;                      // [2][400]

    const bool isG = tid < 200;
    const int  gt  = isG ? tid : 199;              // clamped gate-pair id
    const int  g0 = 2 * gt, g1r = 2 * gt + 1;
    const bool tg = (gt >= 100) && (gt < 150);     // rows 200..299 = g gate
    const int  lidx = (lane < 50) ? lane : 49;

    if (role == 0) {
        // ----------------- LAYER 1 recurrence, chunk ch -----------------
        if (ch >= nch) return;
        const int t0 = ch * Tc, first = (ch == 0);
        unsigned* xs  = (unsigned*)(LB + OFF_XS);  // [2][32][4]
        unsigned* H1R = (unsigned*)(LB + OFF_H1R); // [16][52]
        const bool isX = ((tid & 3) == 1) && (tid < 128);   // um 0..31
        const int  um  = tid >> 2;

        unsigned wA[54], wB[54];
        float bias0, bias1;
        { const float4* p = (const float4*)(w_ih1 + (size_t)g0 * 8);
          float4 v0 = p[0], v1 = p[1];
          wA[0] = packh2(v0.x, v0.y); wA[1] = packh2(v0.z, v0.w);
          wA[2] = packh2(v1.x, v1.y); wA[3] = packh2(v1.z, v1.w); }
        { const float4* p = (const float4*)(w_ih1 + (size_t)g1r * 8);
          float4 v0 = p[0], v1 = p[1];
          wB[0] = packh2(v0.x, v0.y); wB[1] = packh2(v0.z, v0.w);
          wB[2] = packh2(v1.x, v1.y); wB[3] = packh2(v1.z, v1.w); }
        { const float4* p = (const float4*)(w_hh1 + (size_t)g0 * HD);
          #pragma unroll
          for (int q = 0; q < 25; ++q) { float4 v = p[q];
              wA[4 + 2*q] = packh2(v.x, v.y); wA[5 + 2*q] = packh2(v.z, v.w); } }
        { const float4* p = (const float4*)(w_hh1 + (size_t)g1r * HD);
          #pragma unroll
          for (int q = 0; q < 25; ++q) { float4 v = p[q];
              wB[4 + 2*q] = packh2(v.x, v.y); wB[5 + 2*q] = packh2(v.z, v.w); } }
        bias0 = b_ih1[g0] + b_hh1[g0];
        bias1 = b_ih1[g1r] + b_hh1[g1r];

        // replicated state (all waves): lane<50 holds pair `lane`
        float cc0 = 0.f, cc1 = 0.f;
        unsigned hreg = 0u;
        if (!first) {
            hreg = h1buf[((size_t)(Tc - 1) * BB + b) * 52 + lidx];
            if (lane < 50) {
                cc0 = c1s[b * HD + 2 * lane];
                cc1 = c1s[b * HD + 2 * lane + 1];
            }
        } 
        if (isX) {   // stage x chunk 0
            const int s = um;
            const int tt = (t0 + s < TT) ? (t0 + s) : (TT - 1);
            const float4* p = (const float4*)(x + (size_t)(b * TT + tt) * 8);
            float4 v0 = p[0], v1 = p[1];
            xs[(0 * 32 + s) * 4 + 0] = packh2(v0.x, v0.y);
            xs[(0 * 32 + s) * 4 + 1] = packh2(v0.z, v0.w);
            xs[(0 * 32 + s) * 4 + 2] = packh2(v1.x, v1.y);
            xs[(0 * 32 + s) * 4 + 3] = packh2(v1.z, v1.w);
        }
        __syncthreads();

        float4 pa = {0,0,0,0}, pb = {0,0,0,0};
        #pragma unroll 1
        for (int t = 0; t < Tc; ++t) {
            // ---------- P1: gates (branchless, full exec) ----------
            const unsigned st = hreg;              // own register
            const unsigned* xq = xs + (((t >> 5) & 1) * 32 + (t & 31)) * 4;
            unsigned x0 = xq[0], x1 = xq[1], x2 = xq[2], x3 = xq[3];
            float a0 = bias0, a1 = bias1, a2 = 0.f, a3 = 0.f;
            a0 = fdot2(wA[0], x0, a0); a1 = fdot2(wB[0], x0, a1);
            a2 = fdot2(wA[1], x1, a2); a3 = fdot2(wB[1], x1, a3);
            a0 = fdot2(wA[2], x2, a0); a1 = fdot2(wB[2], x2, a1);
            a2 = fdot2(wA[3], x3, a2); a3 = fdot2(wB[3], x3, a3);
            #pragma unroll
            for (int k = 0; k < 50; ++k) {
                unsigned hk = (unsigned)__builtin_amdgcn_readlane((int)st, k);
                if (k & 1) { a2 = fdot2(wA[4 + k], hk, a2); a3 = fdot2(wB[4 + k], hk, a3); }
                else       { a0 = fdot2(wA[4 + k], hk, a0); a1 = fdot2(wB[4 + k], hk, a1); }
            }
            float r0 = a0 + a2, r1 = a1 + a3;
            r0 = tg ? tanh_f(r0) : sigmoid_f(r0);
            r1 = tg ? tanh_f(r1) : sigmoid_f(r1);
            if (isG) *(float2*)(glds + (t & 1) * 400 + 2 * gt) = make_float2(r0, r1);
            __syncthreads();   // the ONLY barrier per step
            // ---------- P2 ----------
            if (isX && (t & 31) == 0 && t + 32 < Tc) {   // issue next x chunk
                const float4* p = (const float4*)(x + (size_t)(b * TT + t0 + t + 32 + um) * 8);
                pa = p[0]; pb = p[1];
            }
            {   // replicated update (all waves)
                const float* g = glds + (t & 1) * 400;
                if (lane < 50) {
                    float2 gi = *(const float2*)(g + 2 * lane);
                    float2 gf = *(const float2*)(g + 100 + 2 * lane);
                    float2 gg = *(const float2*)(g + 200 + 2 * lane);
                    float2 go = *(const float2*)(g + 300 + 2 * lane);
                    cc0 = gf.x * cc0 + gi.x * gg.x;
                    cc1 = gf.y * cc1 + gi.y * gg.y;
                    float h0  = go.x * tanh_f(cc0);
                    float h1v = go.y * tanh_f(cc1);
                    hreg = packh2(h0, h1v);
                    if (w == 0) {
                        H1R[(t & 15) * 52 + lane] = hreg;
                        if (t == Tc - 1) {
                            c1s[b * HD + 2 * lane]     = cc0;
                            c1s[b * HD + 2 * lane + 1] = cc1;
                        }
                    }
                }
            }
            if (isX && (t & 31) == 16) {                 // land x chunk
                const int nb2 = ((t >> 5) + 1) & 1;
                xs[(nb2 * 32 + um) * 4 + 0] = packh2(pa.x, pa.y);
                xs[(nb2 * 32 + um) * 4 + 1] = packh2(pa.z, pa.w);
                xs[(nb2 * 32 + um) * 4 + 2] = packh2(pb.x, pb.y);
                xs[(nb2 * 32 + um) * 4 + 3] = packh2(pb.z, pb.w);
            }
            if ((t & 7) == 3 && t >= 11) {               // flush ring group
                const int s0 = ((t >> 3) - 1) << 3;
                for (int i = tid; i < 400; i += 256) {
                    const int j = i / 50, pr = i - j * 50;
                    h1buf[((size_t)(s0 + j) * BB + b) * 52 + pr] =
                        H1R[((s0 + j) & 15) * 52 + pr];
                }
            }
        }
        __syncthreads();
        {   // tail flush: last group
            const int s0 = Tc - 8;
            for (int i = tid; i < 400; i += 256) {
                const int j = i / 50, pr = i - j * 50;
                h1buf[((size_t)(s0 + j) * BB + b) * 52 + pr] =
                    H1R[((s0 + j) & 15) * 52 + pr];
            }
        }
    } else {
        // ----------------- LAYER 2 recurrence, chunk ch-1 -----------------
        if (ch < 1) return;
        const int first = (ch == 1), last = (ch == nch);
        float* XG = (float*)(LB + OFF_XG);         // [2][8][400]

        unsigned wHA[50], wHB[50];
        { const float4* p = (const float4*)(w_hh2 + (size_t)g0 * HD);
          #pragma unroll
          for (int q = 0; q < 25; ++q) { float4 v = p[q];
              wHA[2*q] = packh2(v.x, v.y); wHA[2*q+1] = packh2(v.z, v.w); } }
        { const float4* p = (const float4*)(w_hh2 + (size_t)g1r * HD);
          #pragma unroll
          for (int q = 0; q < 25; ++q) { float4 v = p[q];
              wHB[2*q] = packh2(v.x, v.y); wHB[2*q+1] = packh2(v.z, v.w); } }

        float cc0 = 0.f, cc1 = 0.f;
        unsigned hreg = 0u;
        if (!first) {
            hreg = h2sp[b * 50 + lidx];
            if (lane < 50) {
                cc0 = c2s[b * HD + 2 * lane];
                cc1 = c2s[b * HD + 2 * lane + 1];
            }
        }
        // preload XG group 0 (steps 0..7)
        #pragma unroll
        for (int j = 0; j < 4; ++j) {
            const int idx = tid + j * 256;     // float4 index, 800 total
            if (idx < 800) {
                const int s = idx / 100, n4 = idx - s * 100;
                *(float4*)&XG[(0 * 8 + s) * 400 + n4 * 4] =
                    *(const float4*)&xg2[((size_t)s * BB + b) * 400 + n4 * 4];
            }
        }
        __syncthreads();

        float4 pre[4];
        #pragma unroll 1
        for (int t = 0; t < Tc; ++t) {
            const int g = t >> 3;
            // ---------- P1: gates ----------
            const unsigned st = hreg;              // own register
            const float2 xg = *(const float2*)&XG[((g & 1) * 8 + (t & 7)) * 400 + 2 * gt];
            float a0 = xg.x, a1 = xg.y, a2 = 0.f, a3 = 0.f;
            #pragma unroll
            for (int k = 0; k < 50; ++k) {
                unsigned hk = (unsigned)__builtin_amdgcn_readlane((int)st, k);
                if (k & 1) { a2 = fdot2(wHA[k], hk, a2); a3 = fdot2(wHB[k], hk, a3); }
                else       { a0 = fdot2(wHA[k], hk, a0); a1 = fdot2(wHB[k], hk, a1); }
            }
            float r0 = a0 + a2, r1 = a1 + a3;
            r0 = tg ? tanh_f(r0) : sigmoid_f(r0);
            r1 = tg ? tanh_f(r1) : sigmoid_f(r1);
            if (isG) *(float2*)(glds + (t & 1) * 400 + 2 * gt) = make_float2(r0, r1);
            __syncthreads();   // the ONLY barrier per step
            // ---------- P2 ----------
            if ((t & 7) == 0 && (g + 1) * 8 < Tc) {      // issue next xg2 group
                #pragma unroll
                for (int j = 0; j < 4; ++j) {
                    const int idx = tid + j * 256;
                    if (idx < 800) {
                        const int s = idx / 100, n4 = idx - s * 100;
                        pre[j] = *(const float4*)
                            &xg2[((size_t)((g + 1) * 8 + s) * BB + b) * 400 + n4 * 4];
                    }
                }
            }
            {   // replicated update (all waves)
                const float* gl = glds + (t & 1) * 400;
                if (lane < 50) {
                    float2 gi = *(const float2*)(gl + 2 * lane);
                    float2 gf = *(const float2*)(gl + 100 + 2 * lane);
                    float2 gg = *(const float2*)(gl + 200 + 2 * lane);
                    float2 go = *(const float2*)(gl + 300 + 2 * lane);
                    cc0 = gf.x * cc0 + gi.x * gg.x;
                    cc1 = gf.y * cc1 + gi.y * gg.y;
                    float h0  = go.x * tanh_f(cc0);
                    float h1v = go.y * tanh_f(cc1);
                    hreg = packh2(h0, h1v);
                    if (w == 0 && t == Tc - 1) {
                        h2sp[b * 50 + lane] = hreg;
                        c2s[b * HD + 2 * lane]     = cc0;
                        c2s[b * HD + 2 * lane + 1] = cc1;
                        if (last) {
                            h2f[b * HD + 2 * lane]     = h0;
                            h2f[b * HD + 2 * lane + 1] = h1v;
                        }
                    }
                }
            }
            if ((t & 7) == 4 && (g + 1) * 8 < Tc) {      // land xg2 group
                #pragma unroll
                for (int j = 0; j < 4; ++j) {
                    const int idx = tid + j * 256;
                    if (idx < 800) {
                        const int s = idx / 100, n4 = idx - s * 100;
                        *(float4*)&XG[(((g + 1) & 1) * 8 + s) * 400 + n4 * 4] = pre[j];
                    }
                }
            }
        }
    }
}

// ============ G: xg2 = h1 . w_ih2^T + biases (MFMA GEMM) ============
__global__ __launch_bounds__(256, 1) void xg2_gemm(
    const unsigned* __restrict__ h1buf,  // [M][52] u32 (+slack)
    const float* __restrict__ w_ih2,     // [400][100] f32
    const float* __restrict__ b_ih2, const float* __restrict__ b_hh2,
    float* __restrict__ xg2,             // [M][400] f32
    int Mrows)
{
    const int tid = threadIdx.x, lane = tid & 63, w = tid >> 6;
    const int W  = blockIdx.x * 4 + w;
    const int mt = W / 25, nt = W - mt * 25;
    if (mt * 16 >= Mrows) return;
    const int col = lane & 15, kg = lane >> 4;
    const int r    = mt * 16 + col;
    const int gate = nt * 16 + col;

    uint4 a[4];
    #pragma unroll
    for (int kt = 0; kt < 4; ++kt)
        a[kt] = *(const uint4*)&h1buf[(size_t)r * 52 + kt * 16 + kg * 4];

    uint4 bf[4];
    #pragma unroll
    for (int kt = 0; kt < 3; ++kt) {
        const float4 va = *(const float4*)&w_ih2[(size_t)gate * HD + kt * 32 + kg * 8];
        const float4 vb = *(const float4*)&w_ih2[(size_t)gate * HD + kt * 32 + kg * 8 + 4];
        bf[kt] = make_uint4(packh2(va.x, va.y), packh2(va.z, va.w),
                            packh2(vb.x, vb.y), packh2(vb.z, vb.w));
    }
    if (kg == 0) {
        const float4 va = *(const float4*)&w_ih2[(size_t)gate * HD + 96];
        bf[3] = make_uint4(packh2(va.x, va.y), packh2(va.z, va.w), 0u, 0u);
    } else {
        bf[3] = make_uint4(0u, 0u, 0u, 0u);
    }

    f32x4 acc = {0.f, 0.f, 0.f, 0.f};
    #pragma unroll
    for (int kt = 0; kt < 4; ++kt) acc = mfma16(a[kt], bf[kt], acc);

    const float bias = b_ih2[gate] + b_hh2[gate];
    #pragma unroll
    for (int j = 0; j < 4; ++j)
        xg2[((size_t)mt * 16 + kg * 4 + j) * 400 + gate] = acc[j] + bias;
}

// ---------------- FC head ----------------
__global__ void fc_head(const float* __restrict__ h2,
                        const float* __restrict__ fc1_w, const float* __restrict__ fc1_b,
                        const float* __restrict__ fc2_w, const float* __restrict__ fc2_b,
                        float* __restrict__ out)
{
    const int bidx = threadIdx.x;
    const float* h = h2 + (size_t)bidx * HD;
    float hv[HD];
    #pragma unroll
    for (int kk = 0; kk < HD / 4; ++kk) {
        float4 v = *(const float4*)(h + 4 * kk);
        hv[4*kk+0] = v.x; hv[4*kk+1] = v.y; hv[4*kk+2] = v.z; hv[4*kk+3] = v.w;
    }
    float y = fc2_b[0];
    #pragma unroll
    for (int m = 0; m < 25; ++m) {
        float a = fc1_b[m];
        const float* wp = fc1_w + m * HD;
        #pragma unroll
        for (int k = 0; k < HD; ++k) a += hv[k] * wp[k];
        y += a * fc2_w[m];
    }
    out[bidx] = y;
}

extern "C" void kernel_launch(void* const* d_in, const int* in_sizes, int n_in,
                              void* d_out, int out_size, void* d_ws, size_t ws_size,
                              hipStream_t stream) {
    const float* x     = (const float*)d_in[0];
    const float* w_ih1 = (const float*)d_in[1];
    const float* w_hh1 = (const float*)d_in[2];
    const float* b_ih1 = (const float*)d_in[3];
    const float* b_hh1 = (const float*)d_in[4];
    const float* w_ih2 = (const float*)d_in[5];
    const float* w_hh2 = (const float*)d_in[6];
    const float* b_ih2 = (const float*)d_in[7];
    const float* b_hh2 = (const float*)d_in[8];
    const float* fc1_w = (const float*)d_in[9];
    const float* fc1_b = (const float*)d_in[10];
    const float* fc2_w = (const float*)d_in[11];
    const float* fc2_b = (const float*)d_in[12];
    float* out = (float*)d_out;

    int Tc = 128;   // multiple of 8, divides TT
    auto need = [](int tc) -> size_t {
        return (size_t)tc * BB * 400 * 4
             + ((size_t)tc * BB * 52 + 64) * 4
             + (size_t)BB * (HD * 3 + 50) * 4;
    };
    while (Tc > 16 && need(Tc) > ws_size) Tc >>= 1;
    const int nch = TT / Tc;
    const int Mrows = Tc * BB;

    float* xg2 = (float*)d_ws;
    unsigned* h1buf = (unsigned*)(xg2 + (size_t)Mrows * 400);
    float* c1s = (float*)(h1buf + (size_t)Mrows * 52 + 64);
    float* c2s = c1s + (size_t)BB * HD;
    float* h2f = c2s + (size_t)BB * HD;
    unsigned* h2sp = (unsigned*)(h2f + (size_t)BB * HD);

    const int gblocks = (Mrows / 16) * 25 / 4;

    for (int ch = 0; ch < nch; ++ch) {
        lstm_rec<<<512, 256, 0, stream>>>(x, w_ih1, w_hh1, b_ih1, b_hh1, w_hh2,
                                          xg2, h1buf, c1s, h2sp, c2s, h2f,
                                          Tc, ch, nch);
        xg2_gemm<<<gblocks, 256, 0, stream>>>(h1buf, w_ih2, b_ih2, b_hh2,
                                              xg2, Mrows);
    }
    lstm_rec<<<512, 256, 0, stream>>>(x, w_ih1, w_hh1, b_ih1, b_hh1, w_hh2,
                                      xg2, h1buf, c1s, h2sp, c2s, h2f,
                                      Tc, nch, nch);
    fc_head<<<1, 256, 0, stream>>>(h2f, fc1_w, fc1_b, fc2_w, fc2_b, out);
}